// Round 1
// baseline (621.930 us; speedup 1.0000x reference)
//
#include <hip/hip_runtime.h>

#define BB 16
#define CH 256
#define NH 4
#define DH 64
#define NN 1024

// ---------------- projection: out[b,o,n] = sum_c W[o,c] x[b,c,n] + bias[o] ----------------
// grid: x = NN/64 (16), y = CH/64 (4), z = b*3+p (48); block 256
__global__ __launch_bounds__(256) void proj_kernel(
    const float* __restrict__ x,
    const float* __restrict__ Wq, const float* __restrict__ bq,
    const float* __restrict__ Wk, const float* __restrict__ bk,
    const float* __restrict__ Wv, const float* __restrict__ bv,
    float* __restrict__ qo, float* __restrict__ ko, float* __restrict__ vo)
{
    const int bz = blockIdx.z;
    const int b = bz / 3, p = bz % 3;
    const float* Wm   = (p == 0) ? Wq : ((p == 1) ? Wk : Wv);
    const float* bias = (p == 0) ? bq : ((p == 1) ? bk : bv);
    float* out = ((p == 0) ? qo : ((p == 1) ? ko : vo)) + (size_t)b * CH * NN;
    const int n0 = blockIdx.x * 64;
    const int m0 = blockIdx.y * 64;

    __shared__ float Ws[32][64];  // [c][o]  (transposed for o-contig reads)
    __shared__ float Xs[32][64];  // [c][n]

    const int tid = threadIdx.x;
    const int to = tid >> 4, tn = tid & 15;
    const float* xb = x + (size_t)b * CH * NN;

    float acc[4][4] = {};

    for (int k0 = 0; k0 < CH; k0 += 32) {
        #pragma unroll
        for (int r = 0; r < 2; ++r) {
            int f = r * 256 + tid;              // 0..511
            int o = f >> 3, c4 = (f & 7) * 4;   // 64 rows x 8 float4
            float4 w4 = *(const float4*)&Wm[(size_t)(m0 + o) * CH + k0 + c4];
            Ws[c4 + 0][o] = w4.x; Ws[c4 + 1][o] = w4.y;
            Ws[c4 + 2][o] = w4.z; Ws[c4 + 3][o] = w4.w;
        }
        #pragma unroll
        for (int r = 0; r < 2; ++r) {
            int f = r * 256 + tid;
            int c = f >> 4, n4 = (f & 15) * 4;  // 32 rows x 16 float4
            *(float4*)&Xs[c][n4] = *(const float4*)&xb[(size_t)(k0 + c) * NN + n0 + n4];
        }
        __syncthreads();
        #pragma unroll
        for (int c = 0; c < 32; ++c) {
            float a[4], xr[4];
            *(float4*)a  = *(const float4*)&Ws[c][to * 4];
            *(float4*)xr = *(const float4*)&Xs[c][tn * 4];
            #pragma unroll
            for (int i = 0; i < 4; ++i)
                #pragma unroll
                for (int j = 0; j < 4; ++j)
                    acc[i][j] = fmaf(a[i], xr[j], acc[i][j]);
        }
        __syncthreads();
    }
    #pragma unroll
    for (int i = 0; i < 4; ++i) {
        float bo = bias[m0 + to * 4 + i];
        float4 r;
        r.x = acc[i][0] + bo; r.y = acc[i][1] + bo;
        r.z = acc[i][2] + bo; r.w = acc[i][3] + bo;
        *(float4*)&out[(size_t)(m0 + to * 4 + i) * NN + n0 + tn * 4] = r;
    }
}

// ---------------- pos[h*64+d][n] = rel_w[h,d,n>>5] + rel_h[h,d,n&31] ----------------
__global__ __launch_bounds__(256) void pos_kernel(
    const float* __restrict__ rel_h, const float* __restrict__ rel_w,
    float* __restrict__ pos)
{
    int idx = blockIdx.x * 256 + threadIdx.x;   // NH*DH*NN = 262144
    if (idx >= NH * DH * NN) return;
    int n  = idx & (NN - 1);
    int hd = idx >> 10;
    pos[idx] = rel_w[hd * 32 + (n >> 5)] + rel_h[hd * 32 + (n & 31)];
}

// ---------------- fused flash attention (fp32) ----------------
// energy[i,j] = sum_d q[d,i]k[d,j] + pos[d,i]q[d,j]  (128-deep with Qe=[q;pos], Ke=[k;q])
// out[d,i] = sum_j softmax_j(energy[i,:]) v[d,j]
// grid: x = NN/64 row tiles (16), y = b*NH+h (64); block 256
__global__ __launch_bounds__(256) void attn_kernel(
    const float* __restrict__ q, const float* __restrict__ k,
    const float* __restrict__ v, const float* __restrict__ pos,
    float* __restrict__ out)
{
    const int bh = blockIdx.y;
    const int b = bh >> 2, h = bh & 3;
    const int ibase = blockIdx.x * 64;

    __shared__ float Qe[128][64];   // [d: q(0..63), pos(64..127)][i]
    __shared__ float Ke[128][64];   // [d: k(0..63), q(64..127)][j]
    __shared__ float Vs[64][68];    // [d][j]   (+4 pad: breaks 4-way bank aliasing)
    __shared__ float Ps[64][68];    // [j][i]   (transposed so PV reads are wide)
    __shared__ float m_s[64], l_s[64], scale_s[64];

    const int tid = threadIdx.x;
    const int ti = tid >> 4, tj = tid & 15;

    const float* qb = q   + (size_t)(b * CH + h * DH) * NN;
    const float* kb = k   + (size_t)(b * CH + h * DH) * NN;
    const float* vb = v   + (size_t)(b * CH + h * DH) * NN;
    const float* pb = pos + (size_t)(h * DH) * NN;

    #pragma unroll
    for (int it = 0; it < 8; ++it) {
        int f = it * 256 + tid;
        int d = f >> 4, c4 = (f & 15) * 4;
        const float* src = (d < 64) ? &qb[(size_t)d * NN + ibase + c4]
                                    : &pb[(size_t)(d - 64) * NN + ibase + c4];
        *(float4*)&Qe[d][c4] = *(const float4*)src;
    }
    if (tid < 64) { m_s[tid] = -1e30f; l_s[tid] = 0.0f; }

    float acc[4][4] = {};   // [dd][ii]: d = 4*ti+dd, i = 4*tj+ii

    for (int jt = 0; jt < 16; ++jt) {
        const int jbase = jt * 64;
        #pragma unroll
        for (int it = 0; it < 8; ++it) {
            int f = it * 256 + tid;
            int d = f >> 4, c4 = (f & 15) * 4;
            const float* src = (d < 64) ? &kb[(size_t)d * NN + jbase + c4]
                                        : &qb[(size_t)(d - 64) * NN + jbase + c4];
            *(float4*)&Ke[d][c4] = *(const float4*)src;
        }
        #pragma unroll
        for (int it = 0; it < 4; ++it) {
            int f = it * 256 + tid;
            int d = f >> 4, c4 = (f & 15) * 4;
            *(float4*)&Vs[d][c4] = *(const float4*)&vb[(size_t)d * NN + jbase + c4];
        }
        __syncthreads();

        // S[i][j], i = 4*ti+ii, j = 4*tj+jj (128-deep)
        float S[4][4] = {};
        for (int d = 0; d < 128; ++d) {
            float qr[4], kr[4];
            *(float4*)qr = *(const float4*)&Qe[d][ti * 4];
            *(float4*)kr = *(const float4*)&Ke[d][tj * 4];
            #pragma unroll
            for (int i = 0; i < 4; ++i)
                #pragma unroll
                for (int j = 0; j < 4; ++j)
                    S[i][j] = fmaf(qr[i], kr[j], S[i][j]);
        }

        // online softmax over this 64-col tile
        #pragma unroll
        for (int i = 0; i < 4; ++i) {
            float rm = fmaxf(fmaxf(S[i][0], S[i][1]), fmaxf(S[i][2], S[i][3]));
            #pragma unroll
            for (int off = 1; off < 16; off <<= 1)
                rm = fmaxf(rm, __shfl_xor(rm, off));
            const int row = ti * 4 + i;
            const float m_old = m_s[row];
            const float m_new = fmaxf(m_old, rm);
            float rs = 0.f;
            #pragma unroll
            for (int j = 0; j < 4; ++j) {
                float pval = __expf(S[i][j] - m_new);
                Ps[tj * 4 + j][row] = pval;
                rs += pval;
            }
            #pragma unroll
            for (int off = 1; off < 16; off <<= 1)
                rs += __shfl_xor(rs, off);
            if (tj == 0) {
                float sc = __expf(m_old - m_new);
                m_s[row] = m_new;
                l_s[row] = l_s[row] * sc + rs;
                scale_s[row] = sc;
            }
        }
        __syncthreads();

        // PV: acc[dd][ii] = sum_j Ps[j][i] * Vs[d][j]
        float sc[4];
        #pragma unroll
        for (int ii = 0; ii < 4; ++ii) sc[ii] = scale_s[tj * 4 + ii];
        #pragma unroll
        for (int dd = 0; dd < 4; ++dd)
            #pragma unroll
            for (int ii = 0; ii < 4; ++ii)
                acc[dd][ii] *= sc[ii];
        for (int jl = 0; jl < 64; ++jl) {
            float pr[4];
            *(float4*)pr = *(const float4*)&Ps[jl][tj * 4];
            float vv[4];
            #pragma unroll
            for (int dd = 0; dd < 4; ++dd) vv[dd] = Vs[ti * 4 + dd][jl];
            #pragma unroll
            for (int dd = 0; dd < 4; ++dd)
                #pragma unroll
                for (int ii = 0; ii < 4; ++ii)
                    acc[dd][ii] = fmaf(vv[dd], pr[ii], acc[dd][ii]);
        }
        __syncthreads();
    }

    float invl[4];
    #pragma unroll
    for (int ii = 0; ii < 4; ++ii) invl[ii] = 1.0f / l_s[tj * 4 + ii];
    #pragma unroll
    for (int dd = 0; dd < 4; ++dd) {
        float4 r;
        r.x = acc[dd][0] * invl[0]; r.y = acc[dd][1] * invl[1];
        r.z = acc[dd][2] * invl[2]; r.w = acc[dd][3] * invl[3];
        *(float4*)&out[(size_t)(b * CH + h * DH + ti * 4 + dd) * NN + ibase + tj * 4] = r;
    }
}

extern "C" void kernel_launch(void* const* d_in, const int* in_sizes, int n_in,
                              void* d_out, int out_size, void* d_ws, size_t ws_size,
                              hipStream_t stream) {
    const float* x     = (const float*)d_in[0];
    const float* Wq    = (const float*)d_in[1];
    const float* bq    = (const float*)d_in[2];
    const float* Wk    = (const float*)d_in[3];
    const float* bk    = (const float*)d_in[4];
    const float* Wv    = (const float*)d_in[5];
    const float* bv    = (const float*)d_in[6];
    const float* rel_h = (const float*)d_in[7];
    const float* rel_w = (const float*)d_in[8];
    // d_in[9] (reg_qk), d_in[10] (reg_v): dead — the reference discards group 4.
    float* out = (float*)d_out;

    float* ws  = (float*)d_ws;
    float* q   = ws;                               // 16*256*1024
    float* k   = q + (size_t)BB * CH * NN;
    float* v   = k + (size_t)BB * CH * NN;
    float* pos = v + (size_t)BB * CH * NN;         // 4*64*1024

    proj_kernel<<<dim3(NN / 64, CH / 64, BB * 3), 256, 0, stream>>>(
        x, Wq, bq, Wk, bk, Wv, bv, q, k, v);
    pos_kernel<<<dim3((NH * DH * NN + 255) / 256), 256, 0, stream>>>(rel_h, rel_w, pos);
    attn_kernel<<<dim3(NN / 64, BB * NH), 256, 0, stream>>>(q, k, v, pos, out);
}

// Round 2
// 260.099 us; speedup vs baseline: 2.3911x; 2.3911x over previous
//
#include <hip/hip_runtime.h>

#define BB 16
#define CH 256
#define NH 4
#define DH 64
#define NN 1024

typedef __bf16 bf16x8 __attribute__((ext_vector_type(8)));
typedef float f32x4 __attribute__((ext_vector_type(4)));

__device__ __forceinline__ unsigned short f2bf(float x) {
    __bf16 b = (__bf16)x;
    return __builtin_bit_cast(unsigned short, b);
}

// ---------------- projection (fp32 math, bf16 hi/lo transposed outputs) ----------------
// out[b,o,n] = sum_c W[o,c] x[b,c,n] + bias[o]
// q,k: write qT/kT [b,h][n][d] bf16 hi+lo.  v: write v_h [b][o][n] bf16 hi.
// grid: x = NN/64 (16), y = CH/64 (4 == NH, so y == head), z = b*3+p (48); block 256
__global__ __launch_bounds__(256) void proj_kernel(
    const float* __restrict__ x,
    const float* __restrict__ Wq, const float* __restrict__ bq,
    const float* __restrict__ Wk, const float* __restrict__ bk,
    const float* __restrict__ Wv, const float* __restrict__ bv,
    unsigned short* __restrict__ qTh, unsigned short* __restrict__ qTl,
    unsigned short* __restrict__ kTh, unsigned short* __restrict__ kTl,
    unsigned short* __restrict__ vH)
{
    const int bz = blockIdx.z;
    const int b = bz / 3, p = bz % 3;
    const float* Wm   = (p == 0) ? Wq : ((p == 1) ? Wk : Wv);
    const float* bias = (p == 0) ? bq : ((p == 1) ? bk : bv);
    const int n0 = blockIdx.x * 64;
    const int m0 = blockIdx.y * 64;
    const int h  = blockIdx.y;          // CH/64 == NH

    __shared__ float Ws[32][64];  // [c][o]
    __shared__ float Xs[32][64];  // [c][n]

    const int tid = threadIdx.x;
    const int to = tid >> 4, tn = tid & 15;
    const float* xb = x + (size_t)b * CH * NN;

    float acc[4][4] = {};

    for (int k0 = 0; k0 < CH; k0 += 32) {
        #pragma unroll
        for (int r = 0; r < 2; ++r) {
            int f = r * 256 + tid;
            int o = f >> 3, c4 = (f & 7) * 4;
            float4 w4 = *(const float4*)&Wm[(size_t)(m0 + o) * CH + k0 + c4];
            Ws[c4 + 0][o] = w4.x; Ws[c4 + 1][o] = w4.y;
            Ws[c4 + 2][o] = w4.z; Ws[c4 + 3][o] = w4.w;
        }
        #pragma unroll
        for (int r = 0; r < 2; ++r) {
            int f = r * 256 + tid;
            int c = f >> 4, n4 = (f & 15) * 4;
            *(float4*)&Xs[c][n4] = *(const float4*)&xb[(size_t)(k0 + c) * NN + n0 + n4];
        }
        __syncthreads();
        #pragma unroll
        for (int c = 0; c < 32; ++c) {
            float a[4], xr[4];
            *(float4*)a  = *(const float4*)&Ws[c][to * 4];
            *(float4*)xr = *(const float4*)&Xs[c][tn * 4];
            #pragma unroll
            for (int i = 0; i < 4; ++i)
                #pragma unroll
                for (int j = 0; j < 4; ++j)
                    acc[i][j] = fmaf(a[i], xr[j], acc[i][j]);
        }
        __syncthreads();
    }

    if (p < 2) {
        unsigned short* dh = ((p == 0) ? qTh : kTh) + (size_t)(b * NH + h) * NN * DH;
        unsigned short* dl = ((p == 0) ? qTl : kTl) + (size_t)(b * NH + h) * NN * DH;
        float bb[4];
        #pragma unroll
        for (int i = 0; i < 4; ++i) bb[i] = bias[m0 + to * 4 + i];
        #pragma unroll
        for (int j = 0; j < 4; ++j) {
            int n = n0 + tn * 4 + j;
            ushort4 vh4, vl4;
            #pragma unroll
            for (int i = 0; i < 4; ++i) {
                float val = acc[i][j] + bb[i];
                __bf16 hb = (__bf16)val;
                float lof = val - (float)hb;
                ((unsigned short*)&vh4)[i] = __builtin_bit_cast(unsigned short, hb);
                ((unsigned short*)&vl4)[i] = f2bf(lof);
            }
            *(ushort4*)&dh[(size_t)n * DH + to * 4] = vh4;
            *(ushort4*)&dl[(size_t)n * DH + to * 4] = vl4;
        }
    } else {
        unsigned short* dv = vH + (size_t)b * CH * NN;
        #pragma unroll
        for (int i = 0; i < 4; ++i) {
            int o = m0 + to * 4 + i;
            float bo = bias[o];
            ushort4 vv;
            #pragma unroll
            for (int j = 0; j < 4; ++j)
                ((unsigned short*)&vv)[j] = f2bf(acc[i][j] + bo);
            *(ushort4*)&dv[(size_t)o * NN + n0 + tn * 4] = vv;
        }
    }
}

// ---------------- pos^T: pTh[h][n][d] = bf16(rel_w[h,d,n>>5] + rel_h[h,d,n&31]) ----------------
__global__ __launch_bounds__(256) void pos_kernel(
    const float* __restrict__ rel_h, const float* __restrict__ rel_w,
    unsigned short* __restrict__ pTh)
{
    int idx = blockIdx.x * 256 + threadIdx.x;     // NH*NN*DH = 262144
    if (idx >= NH * NN * DH) return;
    int d = idx & 63, n = (idx >> 6) & (NN - 1), h = idx >> 16;
    float val = rel_w[(h * DH + d) * 32 + (n >> 5)] + rel_h[(h * DH + d) * 32 + (n & 31)];
    pTh[idx] = f2bf(val);
}

// ---------------- fused flash attention, bf16 MFMA ----------------
// energy[i,j] = sum_{d<128} Qe[d][i] * Ke[d][j], Qe=[q;pos], Ke=[k;q]
// 2-pass split: S = Qh·Kh + Qh·Kl  (K-ext side hi/lo)
// block: 256 thr = 4 waves; wave w owns i-rows [i0+16w, i0+16w+16)
__global__ __launch_bounds__(256) void attn_kernel(
    const unsigned short* __restrict__ qTh, const unsigned short* __restrict__ qTl,
    const unsigned short* __restrict__ kTh, const unsigned short* __restrict__ kTl,
    const unsigned short* __restrict__ vH,  const unsigned short* __restrict__ pTh,
    float* __restrict__ out)
{
    // XCD-bijective swizzle: all 16 i-tiles of one (b,h) on one XCD
    const int wg = blockIdx.x;                       // 0..1023
    const int bh = (wg & 7) * 8 + ((wg >> 3) & 7);   // 0..63
    const int it = wg >> 6;                          // 0..15
    const int b = bh >> 2, h = bh & 3;
    const int i0 = it * 64;

    __shared__ __align__(16) unsigned short Ksh[64][136];   // Ke hi  [j][d], pad 8
    __shared__ __align__(16) unsigned short Ksl[64][136];   // Ke lo
    __shared__ __align__(16) unsigned short Vsh[64][72];    // V [d][j], pad 8
    __shared__ __align__(16) unsigned short Ps[4][16][72];  // per-wave P [i][j], pad 8

    const int tid = threadIdx.x;
    const int wid = tid >> 6, lane = tid & 63;
    const int g = lane >> 4, lr = lane & 15;

    const size_t bhNN = (size_t)(b * NH + h) * NN;
    const unsigned short* qTb  = qTh + bhNN * DH;
    const unsigned short* qTlb = qTl + bhNN * DH;
    const unsigned short* kTb  = kTh + bhNN * DH;
    const unsigned short* kTlb = kTl + bhNN * DH;
    const unsigned short* pTb  = pTh + (size_t)h * NN * DH;
    const unsigned short* vb   = vH + ((size_t)b * CH + h * DH) * NN;

    // Q-ext A-fragments in registers (hi only): k = 32*ks + 8*g + e, row i0+16w+lr
    bf16x8 aQ[4];
    {
        const int i = i0 + wid * 16 + lr;
        #pragma unroll
        for (int ks = 0; ks < 4; ++ks) {
            int d = ks * 32 + g * 8;
            const unsigned short* src = (d < 64) ? &qTb[(size_t)i * DH + d]
                                                 : &pTb[(size_t)i * DH + d - 64];
            aQ[ks] = *(const bf16x8*)src;
        }
    }

    const f32x4 z4 = {0.f, 0.f, 0.f, 0.f};
    f32x4 Oacc[4] = {z4, z4, z4, z4};
    float m_run[4], l_run[4];
    #pragma unroll
    for (int r = 0; r < 4; ++r) { m_run[r] = -1e30f; l_run[r] = 0.f; }

    for (int jt = 0; jt < 16; ++jt) {
        const int jb = jt * 64;
        // ---- stage Ke hi/lo [64][128] and V [64][64] ----
        #pragma unroll
        for (int rep = 0; rep < 2; ++rep) {
            int f = rep * 256 + tid;
            int r = f >> 3, s = f & 7;
            int d0 = s * 16;
            size_t rowoff = (size_t)(jb + r) * DH;
            const unsigned short* sh = (d0 < 64) ? &kTb[rowoff + d0]  : &qTb[rowoff + d0 - 64];
            const unsigned short* sl = (d0 < 64) ? &kTlb[rowoff + d0] : &qTlb[rowoff + d0 - 64];
            *(uint4*)&Ksh[r][d0]     = *(const uint4*)sh;
            *(uint4*)&Ksh[r][d0 + 8] = *(const uint4*)(sh + 8);
            *(uint4*)&Ksl[r][d0]     = *(const uint4*)sl;
            *(uint4*)&Ksl[r][d0 + 8] = *(const uint4*)(sl + 8);
        }
        {
            int r = tid >> 2, s = tid & 3;
            const unsigned short* sv = &vb[(size_t)r * NN + jb + s * 16];
            *(uint4*)&Vsh[r][s * 16]     = *(const uint4*)sv;
            *(uint4*)&Vsh[r][s * 16 + 8] = *(const uint4*)(sv + 8);
        }
        __syncthreads();

        // ---- QK^T: 4 col-fragments x 4 K-steps x 2 passes ----
        f32x4 S[4] = {z4, z4, z4, z4};
        #pragma unroll
        for (int fc = 0; fc < 4; ++fc) {
            const int row = fc * 16 + lr;
            #pragma unroll
            for (int ks = 0; ks < 4; ++ks) {
                bf16x8 bh8 = *(const bf16x8*)&Ksh[row][ks * 32 + g * 8];
                bf16x8 bl8 = *(const bf16x8*)&Ksl[row][ks * 32 + g * 8];
                S[fc] = __builtin_amdgcn_mfma_f32_16x16x32_bf16(aQ[ks], bh8, S[fc], 0, 0, 0);
                S[fc] = __builtin_amdgcn_mfma_f32_16x16x32_bf16(aQ[ks], bl8, S[fc], 0, 0, 0);
            }
        }

        // ---- online softmax (in-register; rows r: i-local = g*4+r) ----
        float p[4][4], sc[4];
        #pragma unroll
        for (int r = 0; r < 4; ++r) {
            float mt = fmaxf(fmaxf(S[0][r], S[1][r]), fmaxf(S[2][r], S[3][r]));
            mt = fmaxf(mt, __shfl_xor(mt, 1));
            mt = fmaxf(mt, __shfl_xor(mt, 2));
            mt = fmaxf(mt, __shfl_xor(mt, 4));
            mt = fmaxf(mt, __shfl_xor(mt, 8));
            float mn = fmaxf(m_run[r], mt);
            sc[r] = __expf(m_run[r] - mn);
            m_run[r] = mn;
            float rs = 0.f;
            #pragma unroll
            for (int fc = 0; fc < 4; ++fc) {
                p[fc][r] = __expf(S[fc][r] - mn);
                rs += p[fc][r];
            }
            rs += __shfl_xor(rs, 1);
            rs += __shfl_xor(rs, 2);
            rs += __shfl_xor(rs, 4);
            rs += __shfl_xor(rs, 8);
            l_run[r] = l_run[r] * sc[r] + rs;
        }
        #pragma unroll
        for (int fc = 0; fc < 4; ++fc)
            #pragma unroll
            for (int r = 0; r < 4; ++r) {
                Oacc[fc][r] *= sc[r];
                Ps[wid][g * 4 + r][fc * 16 + lr] = f2bf(p[fc][r]);
            }

        // ---- PV: O[i][d] += P[i][j] V[d][j]  (wave-private Ps, no barrier) ----
        #pragma unroll
        for (int ks = 0; ks < 2; ++ks) {
            bf16x8 aP = *(const bf16x8*)&Ps[wid][lr][ks * 32 + g * 8];
            #pragma unroll
            for (int fc = 0; fc < 4; ++fc) {
                bf16x8 bV = *(const bf16x8*)&Vsh[fc * 16 + lr][ks * 32 + g * 8];
                Oacc[fc] = __builtin_amdgcn_mfma_f32_16x16x32_bf16(aP, bV, Oacc[fc], 0, 0, 0);
            }
        }
        __syncthreads();
    }

    // ---- epilogue: normalize, transpose via LDS (reuse Ksh: 64*68*4 = 17408 B), store ----
    float inv[4];
    #pragma unroll
    for (int r = 0; r < 4; ++r) inv[r] = 1.0f / l_run[r];

    float (*Os)[68] = (float (*)[68])(&Ksh[0][0]);
    #pragma unroll
    for (int fc = 0; fc < 4; ++fc)
        #pragma unroll
        for (int r = 0; r < 4; ++r)
            Os[fc * 16 + lr][wid * 16 + g * 4 + r] = Oacc[fc][r] * inv[r];
    __syncthreads();

    float* ob = out + ((size_t)b * CH + h * DH) * NN + i0;
    {
        int r = tid >> 2, s = tid & 3;
        #pragma unroll
        for (int q4 = 0; q4 < 4; ++q4)
            *(float4*)&ob[(size_t)r * NN + s * 16 + q4 * 4] = *(const float4*)&Os[r][s * 16 + q4 * 4];
    }
}

extern "C" void kernel_launch(void* const* d_in, const int* in_sizes, int n_in,
                              void* d_out, int out_size, void* d_ws, size_t ws_size,
                              hipStream_t stream) {
    const float* x     = (const float*)d_in[0];
    const float* Wq    = (const float*)d_in[1];
    const float* bq    = (const float*)d_in[2];
    const float* Wk    = (const float*)d_in[3];
    const float* bk    = (const float*)d_in[4];
    const float* Wv    = (const float*)d_in[5];
    const float* bv    = (const float*)d_in[6];
    const float* rel_h = (const float*)d_in[7];
    const float* rel_w = (const float*)d_in[8];
    // d_in[9] (reg_qk), d_in[10] (reg_v): dead — reference discards the register-token group.
    float* out = (float*)d_out;

    const size_t SZ = (size_t)BB * NH * NN * DH;   // 4,194,304 elems (== BB*CH*NN)
    unsigned short* qTh = (unsigned short*)d_ws;
    unsigned short* qTl = qTh + SZ;
    unsigned short* kTh = qTl + SZ;
    unsigned short* kTl = kTh + SZ;
    unsigned short* vH  = kTl + SZ;
    unsigned short* pTh = vH + SZ;                 // NH*NN*DH = 262,144

    proj_kernel<<<dim3(NN / 64, CH / 64, BB * 3), 256, 0, stream>>>(
        x, Wq, bq, Wk, bk, Wv, bv, qTh, qTl, kTh, kTl, vH);
    pos_kernel<<<dim3((NH * NN * DH + 255) / 256), 256, 0, stream>>>(rel_h, rel_w, pTh);
    attn_kernel<<<dim3(1024), 256, 0, stream>>>(qTh, qTl, kTh, kTl, vH, pTh, out);
}

// Round 3
// 158.650 us; speedup vs baseline: 3.9201x; 1.6395x over previous
//
#include <hip/hip_runtime.h>

#define BB 16
#define CH 256
#define NH 4
#define DH 64
#define NN 1024

typedef _Float16 f16x8 __attribute__((ext_vector_type(8)));
typedef float f32x4 __attribute__((ext_vector_type(4)));

__device__ __forceinline__ unsigned short f2h(float x) {
    _Float16 h = (_Float16)x;
    return __builtin_bit_cast(unsigned short, h);
}

// ---------------- W -> fp16 hi/lo ----------------
__global__ __launch_bounds__(256) void prep_kernel(
    const float* __restrict__ Wq, const float* __restrict__ Wk, const float* __restrict__ Wv,
    unsigned short* __restrict__ Wh, unsigned short* __restrict__ Wl)
{
    int idx = blockIdx.x * 256 + threadIdx.x;   // 3*CH*CH = 196608
    if (idx >= 3 * CH * CH) return;
    int p = idx >> 16, oc = idx & 65535;
    const float* W = (p == 0) ? Wq : ((p == 1) ? Wk : Wv);
    float w = W[oc];
    _Float16 h = (_Float16)w;
    Wh[idx] = __builtin_bit_cast(unsigned short, h);
    Wl[idx] = f2h(w - (float)h);
}

// ---------------- x fp32 [b][c][n] -> xT fp16 [b][n][c] ----------------
__global__ __launch_bounds__(256) void xt_kernel(
    const float* __restrict__ x, unsigned short* __restrict__ xT)
{
    const int b = blockIdx.z, c0 = blockIdx.y * 32, n0 = blockIdx.x * 32;
    __shared__ float T[32][33];
    const int t = threadIdx.x;
    {
        int c = t >> 3, n4 = (t & 7) * 4;
        float4 v4 = *(const float4*)&x[((size_t)b * CH + c0 + c) * NN + n0 + n4];
        T[c][n4 + 0] = v4.x; T[c][n4 + 1] = v4.y;
        T[c][n4 + 2] = v4.z; T[c][n4 + 3] = v4.w;
    }
    __syncthreads();
    {
        int n = t >> 3, c4 = (t & 7) * 4;
        ushort4 o;
        o.x = f2h(T[c4 + 0][n]); o.y = f2h(T[c4 + 1][n]);
        o.z = f2h(T[c4 + 2][n]); o.w = f2h(T[c4 + 3][n]);
        *(ushort4*)&xT[((size_t)b * NN + n0 + n) * CH + c0 + c4] = o;
    }
}

// ---------------- pos^T fp16: pT[h][n][d] ----------------
__global__ __launch_bounds__(256) void pos_kernel(
    const float* __restrict__ rel_h, const float* __restrict__ rel_w,
    unsigned short* __restrict__ pT)
{
    int idx = blockIdx.x * 256 + threadIdx.x;     // NH*NN*DH = 262144
    if (idx >= NH * NN * DH) return;
    int d = idx & 63, n = (idx >> 6) & (NN - 1), h = idx >> 16;
    float val = rel_w[(h * DH + d) * 32 + (n >> 5)] + rel_h[(h * DH + d) * 32 + (n & 31)];
    pT[idx] = f2h(val);
}

// ---------------- projection via fp16 MFMA (W hi/lo 2-pass) ----------------
// out[b,o,n] = sum_c W[o,c] x[c,n] + bias[o]
// q,k -> qT/kT fp16 [b,h][n][d] (q scaled by log2e); v -> vH fp16 [b][o][n]
// grid: x = n-tile (16), y = o-tile==head (4), z = b*3+p (48); 256 thr = 4 waves
__global__ __launch_bounds__(256) void proj_kernel(
    const unsigned short* __restrict__ xT,
    const unsigned short* __restrict__ Wh, const unsigned short* __restrict__ Wl,
    const float* __restrict__ bq, const float* __restrict__ bk, const float* __restrict__ bv,
    unsigned short* __restrict__ qT, unsigned short* __restrict__ kT,
    unsigned short* __restrict__ vH)
{
    const int bz = blockIdx.z;
    const int b = bz / 3, p = bz % 3;
    const int n0 = blockIdx.x * 64;
    const int o0 = blockIdx.y * 64;
    const float* bias = (p == 0) ? bq : ((p == 1) ? bk : bv);

    __shared__ __align__(16) unsigned short Xs[64][72];
    __shared__ __align__(16) unsigned short Whs[64][72];
    __shared__ __align__(16) unsigned short Wls[64][72];

    const int tid = threadIdx.x;
    const int wid = tid >> 6, lane = tid & 63;
    const int g = lane >> 4, lr = lane & 15;

    const unsigned short* xb  = xT + (size_t)b * NN * CH;
    const unsigned short* Whp = Wh + (size_t)p * CH * CH;
    const unsigned short* Wlp = Wl + (size_t)p * CH * CH;

    const f32x4 z4 = {0.f, 0.f, 0.f, 0.f};
    f32x4 acc[4] = {z4, z4, z4, z4};

    for (int cs = 0; cs < 4; ++cs) {
        const int c0 = cs * 64;
        __syncthreads();
        #pragma unroll
        for (int rep = 0; rep < 2; ++rep) {
            int f = rep * 256 + tid;
            int r = f >> 3, s = f & 7;
            *(uint4*)&Xs[r][s * 8]  = *(const uint4*)&xb[(size_t)(n0 + r) * CH + c0 + s * 8];
            *(uint4*)&Whs[r][s * 8] = *(const uint4*)&Whp[(size_t)(o0 + r) * CH + c0 + s * 8];
            *(uint4*)&Wls[r][s * 8] = *(const uint4*)&Wlp[(size_t)(o0 + r) * CH + c0 + s * 8];
        }
        __syncthreads();
        #pragma unroll
        for (int ks = 0; ks < 2; ++ks) {
            f16x8 ah = *(const f16x8*)&Whs[wid * 16 + lr][ks * 32 + g * 8];
            f16x8 al = *(const f16x8*)&Wls[wid * 16 + lr][ks * 32 + g * 8];
            #pragma unroll
            for (int fc = 0; fc < 4; ++fc) {
                f16x8 bx = *(const f16x8*)&Xs[fc * 16 + lr][ks * 32 + g * 8];
                acc[fc] = __builtin_amdgcn_mfma_f32_16x16x32_f16(ah, bx, acc[fc], 0, 0, 0);
                acc[fc] = __builtin_amdgcn_mfma_f32_16x16x32_f16(al, bx, acc[fc], 0, 0, 0);
            }
        }
    }

    float bb[4];
    #pragma unroll
    for (int rr = 0; rr < 4; ++rr) bb[rr] = bias[o0 + wid * 16 + g * 4 + rr];

    if (p < 2) {
        const float scale = (p == 0) ? 1.44269504088896f : 1.0f;   // fold log2e into q
        __syncthreads();
        unsigned short (*Os)[72] = Whs;     // reuse as [n-local][o-local]
        #pragma unroll
        for (int fc = 0; fc < 4; ++fc)
            #pragma unroll
            for (int rr = 0; rr < 4; ++rr)
                Os[fc * 16 + lr][wid * 16 + g * 4 + rr] = f2h((acc[fc][rr] + bb[rr]) * scale);
        __syncthreads();
        unsigned short* dst = ((p == 0) ? qT : kT) + ((size_t)(b * NH + blockIdx.y) * NN + n0) * DH;
        #pragma unroll
        for (int rep = 0; rep < 2; ++rep) {
            int f = rep * 256 + tid;
            int r = f >> 3, s = f & 7;
            *(uint4*)&dst[(size_t)r * DH + s * 8] = *(const uint4*)&Os[r][s * 8];
        }
    } else {
        unsigned short* dv = vH + (size_t)b * CH * NN;
        #pragma unroll
        for (int fc = 0; fc < 4; ++fc)
            #pragma unroll
            for (int rr = 0; rr < 4; ++rr) {
                int o = o0 + wid * 16 + g * 4 + rr;
                dv[(size_t)o * NN + n0 + fc * 16 + lr] = f2h(acc[fc][rr] + bb[rr]);
            }
    }
}

// ---------------- fused flash attention, fp16 MFMA + reg-prefetch pipeline ----------------
// energy(log2-domain) = sum_{d<128} Qe[d][i]*Ke[d][j]; Qe=[q*log2e; pos], Ke=[k; q*log2e]
// (q carries log2e: it appears linearly in both cc and cp terms)
__global__ __launch_bounds__(256) void attn_kernel(
    const unsigned short* __restrict__ qT, const unsigned short* __restrict__ kT,
    const unsigned short* __restrict__ vH, const unsigned short* __restrict__ pT,
    float* __restrict__ out)
{
    // XCD-bijective swizzle: the 16 i-tiles of one (b,h) land on one XCD
    const int wg = blockIdx.x;
    const int bh = (wg & 7) * 8 + ((wg >> 3) & 7);
    const int it = wg >> 6;
    const int b = bh >> 2, h = bh & 3;
    const int i0 = it * 64;

    __shared__ __align__(16) unsigned short Ksh[64][136];   // Ke [j][d0..127], pad 8
    __shared__ __align__(16) unsigned short Vsh[64][72];    // V  [d][j], pad 8
    __shared__ __align__(16) unsigned short Ps[4][16][72];  // per-wave P [i][j]

    const int tid = threadIdx.x;
    const int wid = tid >> 6, lane = tid & 63;
    const int g = lane >> 4, lr = lane & 15;

    const size_t bhNN = (size_t)(b * NH + h) * NN;
    const unsigned short* qTb = qT + bhNN * DH;
    const unsigned short* kTb = kT + bhNN * DH;
    const unsigned short* pTb = pT + (size_t)h * NN * DH;
    const unsigned short* vb  = vH + ((size_t)b * CH + h * DH) * NN;

    // Q-ext A-fragments (held in registers for the whole kernel)
    f16x8 aQ[4];
    {
        const int i = i0 + wid * 16 + lr;
        #pragma unroll
        for (int ks = 0; ks < 4; ++ks) {
            int d = ks * 32 + g * 8;
            const unsigned short* src = (d < 64) ? &qTb[(size_t)i * DH + d]
                                                 : &pTb[(size_t)i * DH + d - 64];
            aQ[ks] = *(const f16x8*)src;
        }
    }

    // prefetch tile jt=0 into registers
    uint4 kst[4], vst[2];
    #pragma unroll
    for (int rep = 0; rep < 4; ++rep) {
        int f = rep * 256 + tid;
        int r = f >> 4, s = f & 15;
        const unsigned short* src = (s < 8) ? &kTb[(size_t)r * DH + s * 8]
                                            : &qTb[(size_t)r * DH + (s - 8) * 8];
        kst[rep] = *(const uint4*)src;
    }
    #pragma unroll
    for (int rep = 0; rep < 2; ++rep) {
        int f = rep * 256 + tid;
        int d = f >> 3, j0 = (f & 7) * 8;
        vst[rep] = *(const uint4*)&vb[(size_t)d * NN + j0];
    }

    const f32x4 z4 = {0.f, 0.f, 0.f, 0.f};
    f32x4 Oacc[4] = {z4, z4, z4, z4};
    float m_run[4], l_run[4];
    #pragma unroll
    for (int r = 0; r < 4; ++r) { m_run[r] = -1e30f; l_run[r] = 0.f; }

    for (int jt = 0; jt < 16; ++jt) {
        __syncthreads();    // previous tile's LDS reads complete
        // staged regs -> LDS
        #pragma unroll
        for (int rep = 0; rep < 4; ++rep) {
            int f = rep * 256 + tid;
            int r = f >> 4, s = f & 15;
            *(uint4*)&Ksh[r][s * 8] = kst[rep];
        }
        #pragma unroll
        for (int rep = 0; rep < 2; ++rep) {
            int f = rep * 256 + tid;
            int d = f >> 3, j0 = (f & 7) * 8;
            *(uint4*)&Vsh[d][j0] = vst[rep];
        }
        // issue next tile's global loads (latency hides under compute)
        {
            const int jb2 = ((jt + 1) & 15) * 64;
            #pragma unroll
            for (int rep = 0; rep < 4; ++rep) {
                int f = rep * 256 + tid;
                int r = f >> 4, s = f & 15;
                const unsigned short* src = (s < 8) ? &kTb[(size_t)(jb2 + r) * DH + s * 8]
                                                    : &qTb[(size_t)(jb2 + r) * DH + (s - 8) * 8];
                kst[rep] = *(const uint4*)src;
            }
            #pragma unroll
            for (int rep = 0; rep < 2; ++rep) {
                int f = rep * 256 + tid;
                int d = f >> 3, j0 = (f & 7) * 8;
                vst[rep] = *(const uint4*)&vb[(size_t)d * NN + jb2 + j0];
            }
        }
        __syncthreads();    // LDS visible

        // ---- QK^T: 4 col-blocks x 4 K-steps, single fp16 pass ----
        f32x4 S[4] = {z4, z4, z4, z4};
        #pragma unroll
        for (int fc = 0; fc < 4; ++fc) {
            const int row = fc * 16 + lr;
            #pragma unroll
            for (int ks = 0; ks < 4; ++ks) {
                f16x8 bk8 = *(const f16x8*)&Ksh[row][ks * 32 + g * 8];
                S[fc] = __builtin_amdgcn_mfma_f32_16x16x32_f16(aQ[ks], bk8, S[fc], 0, 0, 0);
            }
        }

        // ---- online softmax, log2 domain ----
        float p[4][4], sc[4];
        #pragma unroll
        for (int r = 0; r < 4; ++r) {
            float mt = fmaxf(fmaxf(S[0][r], S[1][r]), fmaxf(S[2][r], S[3][r]));
            mt = fmaxf(mt, __shfl_xor(mt, 1));
            mt = fmaxf(mt, __shfl_xor(mt, 2));
            mt = fmaxf(mt, __shfl_xor(mt, 4));
            mt = fmaxf(mt, __shfl_xor(mt, 8));
            float mn = fmaxf(m_run[r], mt);
            sc[r] = exp2f(m_run[r] - mn);
            m_run[r] = mn;
            float rs = 0.f;
            #pragma unroll
            for (int fc = 0; fc < 4; ++fc) {
                p[fc][r] = exp2f(S[fc][r] - mn);
                rs += p[fc][r];
            }
            rs += __shfl_xor(rs, 1);
            rs += __shfl_xor(rs, 2);
            rs += __shfl_xor(rs, 4);
            rs += __shfl_xor(rs, 8);
            l_run[r] = l_run[r] * sc[r] + rs;
        }
        #pragma unroll
        for (int fc = 0; fc < 4; ++fc)
            #pragma unroll
            for (int r = 0; r < 4; ++r) {
                Oacc[fc][r] *= sc[r];
                Ps[wid][g * 4 + r][fc * 16 + lr] = f2h(p[fc][r]);
            }

        // ---- PV (wave-private Ps; no barrier) ----
        #pragma unroll
        for (int ks = 0; ks < 2; ++ks) {
            f16x8 aP = *(const f16x8*)&Ps[wid][lr][ks * 32 + g * 8];
            #pragma unroll
            for (int fc = 0; fc < 4; ++fc) {
                f16x8 bV = *(const f16x8*)&Vsh[fc * 16 + lr][ks * 32 + g * 8];
                Oacc[fc] = __builtin_amdgcn_mfma_f32_16x16x32_f16(aP, bV, Oacc[fc], 0, 0, 0);
            }
        }
    }

    // ---- epilogue: normalize, LDS transpose (reuse Ksh), coalesced store ----
    __syncthreads();
    float inv[4];
    #pragma unroll
    for (int r = 0; r < 4; ++r) inv[r] = 1.0f / l_run[r];
    float (*Os)[68] = (float (*)[68])(&Ksh[0][0]);
    #pragma unroll
    for (int fc = 0; fc < 4; ++fc)
        #pragma unroll
        for (int r = 0; r < 4; ++r)
            Os[fc * 16 + lr][wid * 16 + g * 4 + r] = Oacc[fc][r] * inv[r];
    __syncthreads();
    float* ob = out + ((size_t)b * CH + h * DH) * NN + i0;
    #pragma unroll
    for (int rep = 0; rep < 4; ++rep) {
        int f = rep * 256 + tid;
        int r = f >> 4, q4 = f & 15;
        *(float4*)&ob[(size_t)r * NN + q4 * 4] = *(const float4*)&Os[r][q4 * 4];
    }
}

extern "C" void kernel_launch(void* const* d_in, const int* in_sizes, int n_in,
                              void* d_out, int out_size, void* d_ws, size_t ws_size,
                              hipStream_t stream) {
    const float* x     = (const float*)d_in[0];
    const float* Wq    = (const float*)d_in[1];
    const float* bq    = (const float*)d_in[2];
    const float* Wk    = (const float*)d_in[3];
    const float* bk    = (const float*)d_in[4];
    const float* Wv    = (const float*)d_in[5];
    const float* bv    = (const float*)d_in[6];
    const float* rel_h = (const float*)d_in[7];
    const float* rel_w = (const float*)d_in[8];
    // d_in[9] (reg_qk), d_in[10] (reg_v): dead — reference discards the register-token group.
    float* out = (float*)d_out;

    const size_t SZ = (size_t)BB * NH * NN * DH;        // 4,194,304
    unsigned short* qT = (unsigned short*)d_ws;
    unsigned short* kT = qT + SZ;
    unsigned short* vH = kT + SZ;
    unsigned short* pT = vH + SZ;                       // NH*NN*DH = 262,144
    unsigned short* xT = pT + (size_t)NH * NN * DH;     // BB*NN*CH = 4,194,304
    unsigned short* Wh = xT + SZ;                       // 3*CH*CH = 196,608
    unsigned short* Wl = Wh + (size_t)3 * CH * CH;

    prep_kernel<<<dim3((3 * CH * CH + 255) / 256), 256, 0, stream>>>(Wq, Wk, Wv, Wh, Wl);
    xt_kernel<<<dim3(NN / 32, CH / 32, BB), 256, 0, stream>>>(x, xT);
    pos_kernel<<<dim3((NH * NN * DH + 255) / 256), 256, 0, stream>>>(rel_h, rel_w, pT);
    proj_kernel<<<dim3(NN / 64, CH / 64, BB * 3), 256, 0, stream>>>(
        xT, Wh, Wl, bq, bk, bv, qT, kT, vH);
    attn_kernel<<<dim3(1024), 256, 0, stream>>>(qT, kT, vH, pT, out);
}